// Round 6
// baseline (208.298 us; speedup 1.0000x reference)
//
#include <hip/hip_runtime.h>

#define NBH 32      // B*H
#define LL  2048
#define DD  64
#define BQ  64      // q rows per block (one wave)
#define BK  64      // k tile
#define NT  32      // LL/BK
#define CSHIFT 120.0f

typedef _Float16 f16;
typedef _Float16 f16x4 __attribute__((ext_vector_type(4)));
typedef _Float16 f16x8 __attribute__((ext_vector_type(8)));
typedef _Float16 f16x8a __attribute__((ext_vector_type(8), may_alias));
typedef _Float16 f16x4a __attribute__((ext_vector_type(4), may_alias));
typedef float f32x4 __attribute__((ext_vector_type(4)));

__device__ __forceinline__ float elu1(float x) { return x > 0.f ? x + 1.f : __expf(x); }

// Featurize K -> fp16 and transpose V -> Vt[d][k] fp16, one read pass.
__global__ void prep(const float* __restrict__ K, const float* __restrict__ V,
                     f16* __restrict__ Kf, f16* __restrict__ Vt) {
  __shared__ f16 Lt[64][72];
  const int bh = blockIdx.y, r0 = blockIdx.x * 64;
  const int t = threadIdx.x;
#pragma unroll
  for (int it = 0; it < 4; ++it) {
    int idx = t + 256 * it;
    int r = idx >> 4, d0 = (idx & 15) * 4;
    float4 kv = *(const float4*)(K + (size_t)(bh * LL + r0 + r) * DD + d0);
    f16x4 kh = { (f16)elu1(kv.x), (f16)elu1(kv.y), (f16)elu1(kv.z), (f16)elu1(kv.w) };
    *(f16x4a*)(Kf + (size_t)(bh * LL + r0 + r) * DD + d0) = kh;
    float4 vv = *(const float4*)(V + (size_t)(bh * LL + r0 + r) * DD + d0);
    f16x4 vh = { (f16)vv.x, (f16)vv.y, (f16)vv.z, (f16)vv.w };
    *(f16x4a*)&Lt[r][d0] = vh;
  }
  __syncthreads();
  const int w = t >> 6, l = t & 63;
#pragma unroll
  for (int it = 0; it < 2; ++it) {
    int s = w + 4 * it;
    f16x8 o;
#pragma unroll
    for (int j = 0; j < 8; ++j) o[j] = Lt[8 * s + j][l];
    *(f16x8*)(Vt + (size_t)(bh * DD + l) * LL + r0 + 8 * s) = o;
  }
}

// One wave owns 64 q-rows. Zero __syncthreads: K/V MFMA fragments are read as
// b128 directly from global (L2-resident, pre-transposed by prep); only the
// P-transpose buffer Pf lives in LDS and is wave-local (lgkmcnt-ordered).
// Loop1 computes 1/rowsum in regs; loop2 recomputes identical scores, writes
// normalized attn via Pf (full-128B-line nt stores: R3/R4/R5 lessons) and
// accumulates PV.
//   QK: acc = mfma(Kfrag, Qfrag) -> lane holds s[k=16n+4g+i][q=16qg+c]
//   PV: ctx = mfma(Vfrag, Pfrag) -> lane holds ctx[d=16n+4g+i][q=16qg+c]
__launch_bounds__(64, 2)
__global__ void attn_fused(const float* __restrict__ Q, const f16* __restrict__ Kf,
                           const f16* __restrict__ Vt,
                           float* __restrict__ ctx_out, float* __restrict__ attn_out) {
  __shared__ f16 Pf[BQ * BK];   // 8 KB; [q][k] fp16, 16B-slot swizzle phys = slot^(q&7)
  const int bh = blockIdx.y, q0 = blockIdx.x * BQ;
  const int t = threadIdx.x, g = t >> 4, c = t & 15;
  const char* Kh  = (const char*)(Kf + (size_t)bh * LL * DD);
  const char* Vth = (const char*)(Vt + (size_t)bh * DD * LL);
  float* __restrict__ attn_h = attn_out + (size_t)bh * LL * LL;

  // Q fragments from global, featurized in-reg: lane holds Q[16qg+c][32ka+8g+j].
  f16x8 qf[4][2];
#pragma unroll
  for (int qg = 0; qg < 4; ++qg)
#pragma unroll
    for (int ka = 0; ka < 2; ++ka) {
      const float* qp = Q + (size_t)(bh * LL + q0 + 16 * qg + c) * DD + 32 * ka + 8 * g;
      float4 a = *(const float4*)qp;
      float4 b = *(const float4*)(qp + 4);
      f16x8 h = { (f16)elu1(a.x), (f16)elu1(a.y), (f16)elu1(a.z), (f16)elu1(a.w),
                  (f16)elu1(b.x), (f16)elu1(b.y), (f16)elu1(b.z), (f16)elu1(b.w) };
      qf[qg][ka] = h;
    }

  // ---- loop 1: rowsums ----
  float rs[4] = {0.f, 0.f, 0.f, 0.f};
  for (int kt = 0; kt < NT; ++kt) {
    const char* kb = Kh + (size_t)kt * BK * 128;
    f16x8 kfr[4][2];
#pragma unroll
    for (int n = 0; n < 4; ++n)
#pragma unroll
      for (int ka = 0; ka < 2; ++ka)
        kfr[n][ka] = (f16x8)(*(const f16x8a*)(kb + (16 * n + c) * 128 + (4 * ka + g) * 16));
#pragma unroll
    for (int qg = 0; qg < 4; ++qg)
#pragma unroll
      for (int n = 0; n < 4; ++n) {
        f32x4 acc = {0.f, 0.f, 0.f, 0.f};
#pragma unroll
        for (int ka = 0; ka < 2; ++ka)
          acc = __builtin_amdgcn_mfma_f32_16x16x32_f16(kfr[n][ka], qf[qg][ka], acc, 0, 0, 0);
#pragma unroll
        for (int i = 0; i < 4; ++i) rs[qg] += __expf(acc[i] - CSHIFT);
      }
  }
  float inv4[4];
#pragma unroll
  for (int qg = 0; qg < 4; ++qg) {
    float v = rs[qg];
    v += __shfl_xor(v, 16);
    v += __shfl_xor(v, 32);
    inv4[qg] = 1.0f / v;
  }

  // ---- loop 2: recompute, write attn (via Pf transpose), accumulate PV ----
  f32x4 ctx[4][4];
#pragma unroll
  for (int qg = 0; qg < 4; ++qg)
#pragma unroll
    for (int n = 0; n < 4; ++n) ctx[qg][n] = (f32x4){0.f, 0.f, 0.f, 0.f};

  for (int kt = 0; kt < NT; ++kt) {
    const char* kb = Kh + (size_t)kt * BK * 128;
    {
      f16x8 kfr[4][2];
#pragma unroll
      for (int n = 0; n < 4; ++n)
#pragma unroll
        for (int ka = 0; ka < 2; ++ka)
          kfr[n][ka] = (f16x8)(*(const f16x8a*)(kb + (16 * n + c) * 128 + (4 * ka + g) * 16));
#pragma unroll
      for (int qg = 0; qg < 4; ++qg)
#pragma unroll
        for (int n = 0; n < 4; ++n) {
          f32x4 acc = {0.f, 0.f, 0.f, 0.f};
#pragma unroll
          for (int ka = 0; ka < 2; ++ka)
            acc = __builtin_amdgcn_mfma_f32_16x16x32_f16(kfr[n][ka], qf[qg][ka], acc, 0, 0, 0);
          f32x4 p;
#pragma unroll
          for (int i = 0; i < 4; ++i) p[i] = __expf(acc[i] - CSHIFT) * inv4[qg];
          // P[q=16qg+c][k=16n+4g+i] -> swizzled Pf (b64 write, bank-clean)
          f16x4 ph = { (f16)p[0], (f16)p[1], (f16)p[2], (f16)p[3] };
          int slot = (2 * n + (g >> 1)) ^ (c & 7);
          *(f16x4a*)((char*)Pf + (16 * qg + c) * 128 + slot * 16 + (g & 1) * 8) = ph;
        }
    }

    // PV: B-frag pf = P[k=32ka+8g+j][q=16qg+c] (b128 from Pf); A-frag vf direct
    // from global Vt (row = d = 16n+c, 16B k-slice) — reused across all qg.
#pragma unroll
    for (int ka = 0; ka < 2; ++ka) {
      f16x8 vfr[4];
#pragma unroll
      for (int n = 0; n < 4; ++n)
        vfr[n] = (f16x8)(*(const f16x8a*)(Vth + (size_t)(16 * n + c) * (LL * 2) + kt * 128 + (4 * ka + g) * 16));
#pragma unroll
      for (int qg = 0; qg < 4; ++qg) {
        f16x8 pf = (f16x8)(*(const f16x8a*)((const char*)Pf + (16 * qg + c) * 128 + (((4 * ka + g) ^ (c & 7)) << 4)));
#pragma unroll
        for (int n = 0; n < 4; ++n)
          ctx[qg][n] = __builtin_amdgcn_mfma_f32_16x16x32_f16(vfr[n], pf, ctx[qg][n], 0, 0, 0);
      }
    }

    // attn store: b64 LDS read + cvt + nt f32x4 store; wave covers 4 full rows
    // (256B each, full 128B lines) per instruction; 16 insts = the 64x64 tile.
    float* abase = attn_h + (size_t)q0 * LL + kt * BK;
#pragma unroll
    for (int it = 0; it < 16; ++it) {
      int r_loc = 4 * it + g;
      int u = c;                           // 8B unit within the 128B Pf row
      int phys = (((u >> 1) ^ (r_loc & 7)) << 4) + (u & 1) * 8;
      f16x4 hv = *(const f16x4a*)((const char*)Pf + r_loc * 128 + phys);
      f32x4 sv = { (float)hv[0], (float)hv[1], (float)hv[2], (float)hv[3] };
      __builtin_nontemporal_store(sv, (f32x4*)(abase + (size_t)r_loc * LL + 4 * u));
    }
  }

#pragma unroll
  for (int qg = 0; qg < 4; ++qg)
#pragma unroll
    for (int n = 0; n < 4; ++n)
      *(f32x4*)(ctx_out + (size_t)(bh * LL + q0 + 16 * qg + c) * DD + 16 * n + 4 * g) = ctx[qg][n];
}

extern "C" void kernel_launch(void* const* d_in, const int* in_sizes, int n_in,
                              void* d_out, int out_size, void* d_ws, size_t ws_size,
                              hipStream_t stream) {
  const float* Q = (const float*)d_in[0];
  const float* K = (const float*)d_in[1];
  const float* V = (const float*)d_in[2];

  float* ctx_out  = (float*)d_out;                      // [32][2048][64]
  float* attn_out = ctx_out + (size_t)NBH * LL * DD;    // [32][2048][2048]

  f16* Kf = (f16*)d_ws;                                 // featurized K, fp16, 8 MB
  f16* Vt = Kf + (size_t)NBH * LL * DD;                 // V^T per head, fp16, 8 MB

  hipLaunchKernelGGL(prep, dim3(LL / 64, NBH), dim3(256), 0, stream, K, V, Kf, Vt);
  hipLaunchKernelGGL(attn_fused, dim3(LL / BQ, NBH), dim3(64), 0, stream,
                     Q, Kf, Vt, ctx_out, attn_out);
}

// Round 7
// 159.973 us; speedup vs baseline: 1.3021x; 1.3021x over previous
//
#include <hip/hip_runtime.h>

#define NBH 32      // B*H
#define LL  2048
#define DD  64
#define BQ  64      // q rows per block
#define BK  64      // k tile
#define NT  32      // LL/BK
#define CSHIFT 120.0f

typedef _Float16 f16;
typedef _Float16 f16x4 __attribute__((ext_vector_type(4)));
typedef _Float16 f16x8 __attribute__((ext_vector_type(8)));
typedef _Float16 f16x8a __attribute__((ext_vector_type(8), may_alias));
typedef _Float16 f16x4a __attribute__((ext_vector_type(4), may_alias));
typedef float f32x4 __attribute__((ext_vector_type(4)));

#define SBARR() __builtin_amdgcn_sched_barrier(0)
#define BARRIER() do { SBARR(); __builtin_amdgcn_s_barrier(); SBARR(); } while (0)
#define WAITVM(N) do { SBARR(); asm volatile("s_waitcnt vmcnt(" #N ")" ::: "memory"); SBARR(); } while (0)

__device__ __forceinline__ float elu1(float x) { return x > 0.f ? x + 1.f : __expf(x); }

__device__ __forceinline__ void gl_lds16(const void* src, void* lds_dst) {
  __builtin_amdgcn_global_load_lds((const __attribute__((address_space(1))) unsigned int*)src,
                                   (__attribute__((address_space(3))) unsigned int*)lds_dst,
                                   16, 0, 0);
}

// Stage a 64-row x 128B tile into 8KB LDS (linear dest, 2 gl_lds per thread).
// Content swizzled: LDS 16B-slot s of row r holds global slot s^(r&7).
__device__ __forceinline__ void stage_tile(const char* gbase, size_t grow, f16* lds, int w, int l) {
#pragma unroll
  for (int c2 = 0; c2 < 2; ++c2) {
    int U = w * 128 + c2 * 64 + l;       // 16B unit id
    int r = U >> 3, sp = U & 7;
    gl_lds16(gbase + (size_t)r * grow + ((sp ^ (r & 7)) << 4),
             (char*)lds + w * 2048 + c2 * 1024);   // wave-uniform base; HW adds lane*16
  }
}

// Featurize K -> fp16 and transpose V -> Vt[d][k] fp16, one read pass.
__global__ void prep(const float* __restrict__ K, const float* __restrict__ V,
                     f16* __restrict__ Kf, f16* __restrict__ Vt) {
  __shared__ f16 Lt[64][72];
  const int bh = blockIdx.y, r0 = blockIdx.x * 64;
  const int t = threadIdx.x;
#pragma unroll
  for (int it = 0; it < 4; ++it) {
    int idx = t + 256 * it;
    int r = idx >> 4, d0 = (idx & 15) * 4;
    float4 kv = *(const float4*)(K + (size_t)(bh * LL + r0 + r) * DD + d0);
    f16x4 kh = { (f16)elu1(kv.x), (f16)elu1(kv.y), (f16)elu1(kv.z), (f16)elu1(kv.w) };
    *(f16x4a*)(Kf + (size_t)(bh * LL + r0 + r) * DD + d0) = kh;
    float4 vv = *(const float4*)(V + (size_t)(bh * LL + r0 + r) * DD + d0);
    f16x4 vh = { (f16)vv.x, (f16)vv.y, (f16)vv.z, (f16)vv.w };
    *(f16x4a*)&Lt[r][d0] = vh;
  }
  __syncthreads();
  const int w = t >> 6, l = t & 63;
#pragma unroll
  for (int it = 0; it < 2; ++it) {
    int s = w + 4 * it;
    f16x8 o;
#pragma unroll
    for (int j = 0; j < 8; ++j) o[j] = Lt[8 * s + j][l];
    *(f16x8*)(Vt + (size_t)(bh * DD + l) * LL + r0 + 8 * s) = o;
  }
}

// R5 structure + counted-vmcnt raw barriers (T3/T4): per k-tile
//   P1 stage(next) -> P2 s_waitcnt vmcnt(N) [own current-tile loads landed;
//   stores + next-tile loads stay in flight] -> P3 s_barrier -> P4 compute
//   (+16 nt stores) -> P5 s_barrier.
// N derivation (in-order vmcnt retirement): steady loop2 outstanding order =
// [L_kt(4), S_{kt-1}(16), L_{kt+1}(4)] -> N=20. Loop1: [L_kt(2), L_{kt+1}(2)]
// -> N=2. Transitions peeled for exact counts.
__launch_bounds__(256, 4)
__global__ void attn_fused(const float* __restrict__ Q, const f16* __restrict__ Kf,
                           const f16* __restrict__ Vt,
                           float* __restrict__ ctx_out, float* __restrict__ attn_out) {
  __shared__ f16 Ks[2][BK * DD];
  __shared__ f16 Vs[2][BK * DD];
  __shared__ f16 Pf[BQ * BK];   // [q][k] fp16, 16B-slot swizzle phys = slot^(q&7)
  const int bh = blockIdx.y, q0 = blockIdx.x * BQ;
  const int t = threadIdx.x, w = t >> 6, l = t & 63, g = l >> 4, c = l & 15;
  const char* Kh  = (const char*)(Kf + (size_t)bh * LL * DD);
  const char* Vth = (const char*)(Vt + (size_t)bh * DD * LL);
  float* __restrict__ attn_h = attn_out + (size_t)bh * LL * LL;

  // Q fragments from global, featurized in-reg (immediate consumption -> no
  // lingering vmcnt entries). Lane holds Q[row=16w+c][d=32ka+8g+j].
  const int qrow = q0 + 16 * w + c;
  f16x8 qf[2];
#pragma unroll
  for (int ka = 0; ka < 2; ++ka) {
    const float* qp = Q + (size_t)(bh * LL + qrow) * DD + 32 * ka + 8 * g;
    float4 a = *(const float4*)qp;
    float4 b = *(const float4*)(qp + 4);
    f16x8 h = { (f16)elu1(a.x), (f16)elu1(a.y), (f16)elu1(a.z), (f16)elu1(a.w),
                (f16)elu1(b.x), (f16)elu1(b.y), (f16)elu1(b.z), (f16)elu1(b.w) };
    qf[ka] = h;
  }

  float rs = 0.f;
  auto rowsum_tile = [&](const f16* KbT) {
    const char* Kb = (const char*)KbT;
#pragma unroll
    for (int n = 0; n < 4; ++n) {
      f32x4 acc = {0.f, 0.f, 0.f, 0.f};
#pragma unroll
      for (int ka = 0; ka < 2; ++ka) {
        int row = n * 16 + c;
        f16x8 kfr = (f16x8)(*(const f16x8a*)(Kb + row * 128 + (((4 * ka + g) ^ (row & 7)) << 4)));
        acc = __builtin_amdgcn_mfma_f32_16x16x32_f16(kfr, qf[ka], acc, 0, 0, 0);
      }
#pragma unroll
      for (int i = 0; i < 4; ++i) rs += __expf(acc[i] - CSHIFT);
    }
  };

  f32x4 ctx[4];
#pragma unroll
  for (int n = 0; n < 4; ++n) ctx[n] = (f32x4){0.f, 0.f, 0.f, 0.f};
  float inv = 0.f;

  auto main_tile = [&](int kt, const f16* KbT, const f16* VbT) {
    const char* Kb = (const char*)KbT;
    const char* Vb = (const char*)VbT;
#pragma unroll
    for (int n = 0; n < 4; ++n) {
      f32x4 acc = {0.f, 0.f, 0.f, 0.f};
#pragma unroll
      for (int ka = 0; ka < 2; ++ka) {
        int row = n * 16 + c;
        f16x8 kfr = (f16x8)(*(const f16x8a*)(Kb + row * 128 + (((4 * ka + g) ^ (row & 7)) << 4)));
        acc = __builtin_amdgcn_mfma_f32_16x16x32_f16(kfr, qf[ka], acc, 0, 0, 0);
      }
      f32x4 p;
#pragma unroll
      for (int i = 0; i < 4; ++i) p[i] = __expf(acc[i] - CSHIFT) * inv;  // normalized
      f16x4 ph = { (f16)p[0], (f16)p[1], (f16)p[2], (f16)p[3] };
      int slot = (2 * n + (g >> 1)) ^ (c & 7);
      *(f16x4a*)((char*)Pf + (16 * w + c) * 128 + slot * 16 + (g & 1) * 8) = ph;
    }
    // PV: A-frag from Vs, B-frag from Pf (all wave-local rows; lgkm-ordered)
#pragma unroll
    for (int ka = 0; ka < 2; ++ka) {
      f16x8 pf = (f16x8)(*(const f16x8a*)((const char*)Pf + (16 * w + c) * 128 + (((4 * ka + g) ^ (c & 7)) << 4)));
#pragma unroll
      for (int n = 0; n < 4; ++n) {
        int row = n * 16 + c;
        f16x8 vf = (f16x8)(*(const f16x8a*)(Vb + row * 128 + (((4 * ka + g) ^ (row & 7)) << 4)));
        ctx[n] = __builtin_amdgcn_mfma_f32_16x16x32_f16(vf, pf, ctx[n], 0, 0, 0);
      }
    }
    // attn store: b64 LDS read + cvt + nt f32x4; wave covers 4 full rows/inst
    float* abase = attn_h + (size_t)q0 * LL + kt * BK;
#pragma unroll
    for (int it = 0; it < 4; ++it) {
      int r_loc = 16 * w + 4 * it + (l >> 4);
      int u = l & 15;
      int phys = (((u >> 1) ^ (r_loc & 7)) << 4) + (u & 1) * 8;
      f16x4 hv = *(const f16x4a*)((const char*)Pf + r_loc * 128 + phys);
      f32x4 sv = { (float)hv[0], (float)hv[1], (float)hv[2], (float)hv[3] };
      __builtin_nontemporal_store(sv, (f32x4*)(abase + (size_t)r_loc * LL + 4 * u));
    }
  };

  // ================= loop 1: rowsums =================
  stage_tile(Kh, 128, Ks[0], w, l);                       // L_0 (2 loads)
  for (int kt = 0; kt < NT - 1; ++kt) {
    stage_tile(Kh + (size_t)(kt + 1) * BK * 128, 128, Ks[(kt + 1) & 1], w, l);  // 2 loads
    WAITVM(2);          // L_kt landed (own)
    BARRIER();          // all waves' L_kt landed
    rowsum_tile(Ks[kt & 1]);
    BARRIER();          // reads done -> buffer may be overwritten next iter
  }
  // peeled kt=31: stage loop2's tile 0 (K0 + V0, 4 loads)
  stage_tile(Kh, 128, Ks[0], w, l);
  stage_tile(Vth, (size_t)LL * 2, Vs[0], w, l);
  WAITVM(4);
  BARRIER();
  rowsum_tile(Ks[1]);
  BARRIER();

  rs += __shfl_xor(rs, 16);
  rs += __shfl_xor(rs, 32);
  inv = 1.0f / rs;

  // ================= loop 2: recompute + attn + PV =================
  // peeled iter 0 (no stores outstanding yet -> N=4)
  stage_tile(Kh + (size_t)BK * 128, 128, Ks[1], w, l);
  stage_tile(Vth + (size_t)BK * 2, (size_t)LL * 2, Vs[1], w, l);
  WAITVM(4);
  BARRIER();
  main_tile(0, Ks[0], Vs[0]);   // issues S_0 (16 nt stores)
  BARRIER();
  for (int kt = 1; kt < NT; ++kt) {
    int nxt = (kt + 1) & (NT - 1);   // kt=31 restages tile0 (dead but harmless)
    stage_tile(Kh + (size_t)nxt * BK * 128, 128, Ks[(kt + 1) & 1], w, l);
    stage_tile(Vth + (size_t)nxt * BK * 2, (size_t)LL * 2, Vs[(kt + 1) & 1], w, l);
    WAITVM(20);         // L_kt done; S_{kt-1}(16)+L_{kt+1}(4) may remain in flight
    BARRIER();
    main_tile(kt, Ks[kt & 1], Vs[kt & 1]);
    BARRIER();
  }

#pragma unroll
  for (int n = 0; n < 4; ++n)
    *(f32x4*)(ctx_out + (size_t)(bh * LL + qrow) * DD + n * 16 + 4 * g) = ctx[n];
}

extern "C" void kernel_launch(void* const* d_in, const int* in_sizes, int n_in,
                              void* d_out, int out_size, void* d_ws, size_t ws_size,
                              hipStream_t stream) {
  const float* Q = (const float*)d_in[0];
  const float* K = (const float*)d_in[1];
  const float* V = (const float*)d_in[2];

  float* ctx_out  = (float*)d_out;                      // [32][2048][64]
  float* attn_out = ctx_out + (size_t)NBH * LL * DD;    // [32][2048][2048]

  f16* Kf = (f16*)d_ws;                                 // featurized K, fp16, 8 MB
  f16* Vt = Kf + (size_t)NBH * LL * DD;                 // V^T per head, fp16, 8 MB

  hipLaunchKernelGGL(prep, dim3(LL / 64, NBH), dim3(256), 0, stream, K, V, Kf, Vt);
  hipLaunchKernelGGL(attn_fused, dim3(LL / BQ, NBH), dim3(256), 0, stream,
                     Q, Kf, Vt, ctx_out, attn_out);
}